// Round 1
// baseline (39.299 us; speedup 1.0000x reference)
//
#include <hip/hip_runtime.h>

// DeformableQuantizer: x[8,4096,768] fp32, delta[8,3] fp32, deform_scale scalar.
// Forward value of straight-through estimator == quantized.
// Per group of 3: logit_k = z . (2*cb_k/T) - |cb_k|^2/T  (z-norm cancels in softmax),
// weights = softmax(logit), out = weights @ cb.

#define TEMP_INV (1.0f / 0.3f)

__global__ __launch_bounds__(256) void dq_kernel(
    const float* __restrict__ x,
    const float* __restrict__ delta,
    const float* __restrict__ scale_p,
    float* __restrict__ out,
    int nchunks)  // number of 4-group (12-float) chunks
{
    const int idx = blockIdx.x * blockDim.x + threadIdx.x;

    // Build deformed codebook. BASE_CODEBOOK row k, dim d: bit (2-d) of k -> +/-1.
    const float s = *scale_p;
    float cb[8][3];   // deformed codebook
    float w[8][3];    // 2*cb/T
    float b[8];       // -|cb|^2 / T
    #pragma unroll
    for (int k = 0; k < 8; ++k) {
        #pragma unroll
        for (int d = 0; d < 3; ++d) {
            const float base = ((k >> (2 - d)) & 1) ? 1.0f : -1.0f;
            const float c = fmaf(s, delta[k * 3 + d], base);
            cb[k][d] = c;
            w[k][d] = 2.0f * TEMP_INV * c;
        }
        b[k] = -(cb[k][0] * cb[k][0] + cb[k][1] * cb[k][1] + cb[k][2] * cb[k][2]) * TEMP_INV;
    }

    if (idx >= nchunks) return;

    const float4* xin = reinterpret_cast<const float4*>(x) + (size_t)idx * 3;
    const float4 v0 = xin[0], v1 = xin[1], v2 = xin[2];
    float zin[12] = {v0.x, v0.y, v0.z, v0.w,
                     v1.x, v1.y, v1.z, v1.w,
                     v2.x, v2.y, v2.z, v2.w};
    float zo[12];

    #pragma unroll
    for (int g = 0; g < 4; ++g) {
        const float z0 = zin[g * 3 + 0];
        const float z1 = zin[g * 3 + 1];
        const float z2 = zin[g * 3 + 2];

        float logit[8];
        float m = -1e30f;
        #pragma unroll
        for (int k = 0; k < 8; ++k) {
            const float l = fmaf(z0, w[k][0], fmaf(z1, w[k][1], fmaf(z2, w[k][2], b[k])));
            logit[k] = l;
            m = fmaxf(m, l);
        }

        float e[8];
        float sum = 0.0f;
        #pragma unroll
        for (int k = 0; k < 8; ++k) {
            e[k] = __expf(logit[k] - m);
            sum += e[k];
        }
        const float inv = 1.0f / sum;

        float q0 = 0.0f, q1 = 0.0f, q2 = 0.0f;
        #pragma unroll
        for (int k = 0; k < 8; ++k) {
            q0 = fmaf(e[k], cb[k][0], q0);
            q1 = fmaf(e[k], cb[k][1], q1);
            q2 = fmaf(e[k], cb[k][2], q2);
        }
        zo[g * 3 + 0] = q0 * inv;
        zo[g * 3 + 1] = q1 * inv;
        zo[g * 3 + 2] = q2 * inv;
    }

    float4* o = reinterpret_cast<float4*>(out) + (size_t)idx * 3;
    o[0] = make_float4(zo[0], zo[1], zo[2], zo[3]);
    o[1] = make_float4(zo[4], zo[5], zo[6], zo[7]);
    o[2] = make_float4(zo[8], zo[9], zo[10], zo[11]);
}

extern "C" void kernel_launch(void* const* d_in, const int* in_sizes, int n_in,
                              void* d_out, int out_size, void* d_ws, size_t ws_size,
                              hipStream_t stream) {
    const float* x     = (const float*)d_in[0];
    const float* delta = (const float*)d_in[1];
    const float* scale = (const float*)d_in[2];
    float* out = (float*)d_out;

    const int total = out_size;           // 8*4096*768 = 25,165,824 floats
    const int nchunks = total / 12;       // 2,097,152 chunks of 4 groups
    const int block = 256;
    const int grid = (nchunks + block - 1) / block;  // 8192

    dq_kernel<<<grid, block, 0, stream>>>(x, delta, scale, out, nchunks);
}

// Round 2
// 35.150 us; speedup vs baseline: 1.1180x; 1.1180x over previous
//
#include <hip/hip_runtime.h>

// DeformableQuantizer forward == quantized (straight-through).
// softmax(-dists/T) = softmax((2 z.cb - |cb|^2)/T)   (z^2 cancels across k)
// exp2 domain: logit_k = z . w_k + b_k,  w_k = 2 cb_k/(T ln2),  b_k = -|cb_k|^2/(T ln2)
// out_d = K * (sum_k e_k w_kd) * rcp(sum_k e_k),  K = T ln2 / 2   (since cb = K w)

#define TEMP 0.3f
#define LN2  0.6931471805599453f

__global__ __launch_bounds__(256) void dq_kernel(
    const float* __restrict__ x,
    const float* __restrict__ delta,
    const float* __restrict__ scale_p,
    float* __restrict__ out)
{
    __shared__ float4 lin[768];   // 12 KB
    __shared__ float4 lout[768];  // 12 KB

    const int t = threadIdx.x;
    const size_t base4 = (size_t)blockIdx.x * 768;  // float4 units

    // ---- coalesced global -> LDS (lane-contiguous float4) ----
    const float4* xin = reinterpret_cast<const float4*>(x) + base4;
    const float4 g0 = xin[t];
    const float4 g1 = xin[t + 256];
    const float4 g2 = xin[t + 512];

    // ---- codebook (uniform; overlaps the load latency) ----
    const float s = *scale_p;
    const float c1 = 2.0f / (TEMP * LN2);   // w scale
    const float c2 = 1.0f / (TEMP * LN2);   // b scale
    const float K  = TEMP * LN2 * 0.5f;     // cb = K * w
    float w0[8], w1[8], w2[8], b[8];
    #pragma unroll
    for (int k = 0; k < 8; ++k) {
        const float d0 = fmaf(s, delta[k * 3 + 0], (k & 4) ? 1.0f : -1.0f);
        const float d1 = fmaf(s, delta[k * 3 + 1], (k & 2) ? 1.0f : -1.0f);
        const float d2 = fmaf(s, delta[k * 3 + 2], (k & 1) ? 1.0f : -1.0f);
        w0[k] = c1 * d0;
        w1[k] = c1 * d1;
        w2[k] = c1 * d2;
        b[k]  = -(d0 * d0 + d1 * d1 + d2 * d2) * c2;
    }

    lin[t]       = g0;
    lin[t + 256] = g1;
    lin[t + 512] = g2;
    __syncthreads();

    // ---- compute: thread t owns floats [12t, 12t+12) of the tile ----
    // ds_read_b128 at byte 48*t: bank-quad (3t)&7 is bijective per 8 lanes -> conflict-free
    const float4 a0 = lin[3 * t + 0];
    const float4 a1 = lin[3 * t + 1];
    const float4 a2 = lin[3 * t + 2];
    const float zin[12] = {a0.x, a0.y, a0.z, a0.w,
                           a1.x, a1.y, a1.z, a1.w,
                           a2.x, a2.y, a2.z, a2.w};
    float zo[12];

    #pragma unroll
    for (int g = 0; g < 4; ++g) {
        const float z0 = zin[g * 3 + 0];
        const float z1 = zin[g * 3 + 1];
        const float z2 = zin[g * 3 + 2];

        float logit[8];
        float m = -1e30f;
        #pragma unroll
        for (int k = 0; k < 8; ++k) {
            const float l = fmaf(z0, w0[k], fmaf(z1, w1[k], fmaf(z2, w2[k], b[k])));
            logit[k] = l;
            m = fmaxf(m, l);
        }

        float e[8];
        float sum = 0.0f;
        #pragma unroll
        for (int k = 0; k < 8; ++k) {
            e[k] = __builtin_amdgcn_exp2f(logit[k] - m);
            sum += e[k];
        }
        const float inv = K * __builtin_amdgcn_rcpf(sum);

        float q0 = 0.0f, q1 = 0.0f, q2 = 0.0f;
        #pragma unroll
        for (int k = 0; k < 8; ++k) {
            q0 = fmaf(e[k], w0[k], q0);
            q1 = fmaf(e[k], w1[k], q1);
            q2 = fmaf(e[k], w2[k], q2);
        }
        zo[g * 3 + 0] = q0 * inv;
        zo[g * 3 + 1] = q1 * inv;
        zo[g * 3 + 2] = q2 * inv;
    }

    lout[3 * t + 0] = make_float4(zo[0], zo[1],  zo[2],  zo[3]);
    lout[3 * t + 1] = make_float4(zo[4], zo[5],  zo[6],  zo[7]);
    lout[3 * t + 2] = make_float4(zo[8], zo[9],  zo[10], zo[11]);
    __syncthreads();

    // ---- coalesced LDS -> global ----
    float4* o = reinterpret_cast<float4*>(out) + base4;
    o[t]       = lout[t];
    o[t + 256] = lout[t + 256];
    o[t + 512] = lout[t + 512];
}

extern "C" void kernel_launch(void* const* d_in, const int* in_sizes, int n_in,
                              void* d_out, int out_size, void* d_ws, size_t ws_size,
                              hipStream_t stream) {
    const float* x     = (const float*)d_in[0];
    const float* delta = (const float*)d_in[1];
    const float* scale = (const float*)d_in[2];
    float* out = (float*)d_out;

    const int grid = out_size / 3072;  // 25,165,824 / 3072 = 8192 blocks exactly
    dq_kernel<<<grid, 256, 0, stream>>>(x, delta, scale, out);
}

// Round 7
// 34.962 us; speedup vs baseline: 1.1240x; 1.0054x over previous
//
#include <hip/hip_runtime.h>

// DeformableQuantizer forward == quantized (straight-through).
// softmax(-dists/T) = softmax((2 z.cb - |cb|^2)/T)   (z^2 cancels across k)
// exp2 domain: logit_k = z . w_k + b_k,  w_k = 2 cb_k/(T ln2),  b_k = -|cb_k|^2/(T ln2)
// out_d = K * (sum_k e_k w_kd) * rcp(sum_k e_k),  K = T ln2 / 2   (since cb = K w)

#define TEMP 0.3f
#define LN2  0.6931471805599453f

// native clang vector type — required by __builtin_nontemporal_store
typedef float floatx4 __attribute__((ext_vector_type(4)));

__global__ __launch_bounds__(256) void dq_kernel(
    const float* __restrict__ x,
    const float* __restrict__ delta,
    const float* __restrict__ scale_p,
    float* __restrict__ out)
{
    // Single 12 KB buffer, reused for input and output.
    // Safe: compute phase reads buf[3t+i] then writes buf[3t+i] — same thread,
    // disjoint across threads; barriers separate the coalesced phases.
    __shared__ float4 buf[768];

    const int t = threadIdx.x;
    const size_t base4 = (size_t)blockIdx.x * 768;  // float4 units

    // ---- coalesced global -> LDS (lane-contiguous float4) ----
    const float4* xin = reinterpret_cast<const float4*>(x) + base4;
    const float4 g0 = xin[t];
    const float4 g1 = xin[t + 256];
    const float4 g2 = xin[t + 512];

    // ---- codebook (uniform; overlaps the load latency) ----
    const float s = *scale_p;
    const float c1 = 2.0f / (TEMP * LN2);   // w scale
    const float c2 = 1.0f / (TEMP * LN2);   // b scale
    const float K  = TEMP * LN2 * 0.5f;     // cb = K * w
    float w0[8], w1[8], w2[8], b[8];
    #pragma unroll
    for (int k = 0; k < 8; ++k) {
        const float d0 = fmaf(s, delta[k * 3 + 0], (k & 4) ? 1.0f : -1.0f);
        const float d1 = fmaf(s, delta[k * 3 + 1], (k & 2) ? 1.0f : -1.0f);
        const float d2 = fmaf(s, delta[k * 3 + 2], (k & 1) ? 1.0f : -1.0f);
        w0[k] = c1 * d0;
        w1[k] = c1 * d1;
        w2[k] = c1 * d2;
        b[k]  = -(d0 * d0 + d1 * d1 + d2 * d2) * c2;
    }

    buf[t]       = g0;
    buf[t + 256] = g1;
    buf[t + 512] = g2;
    __syncthreads();

    // ---- compute: thread t owns floats [12t, 12t+12) of the tile ----
    // ds_read_b128 at byte 48*t: bank-quad (3t)&7 bijective per 8 lanes -> conflict-free
    const float4 a0 = buf[3 * t + 0];
    const float4 a1 = buf[3 * t + 1];
    const float4 a2 = buf[3 * t + 2];
    const float zin[12] = {a0.x, a0.y, a0.z, a0.w,
                           a1.x, a1.y, a1.z, a1.w,
                           a2.x, a2.y, a2.z, a2.w};
    float zo[12];

    #pragma unroll
    for (int g = 0; g < 4; ++g) {
        const float z0 = zin[g * 3 + 0];
        const float z1 = zin[g * 3 + 1];
        const float z2 = zin[g * 3 + 2];

        float logit[8];
        #pragma unroll
        for (int k = 0; k < 8; ++k)
            logit[k] = fmaf(z0, w0[k], fmaf(z1, w1[k], fmaf(z2, w2[k], b[k])));

        // max3-friendly reduction tree
        float m = fmaxf(fmaxf(logit[0], logit[1]), logit[2]);
        m = fmaxf(fmaxf(m, logit[3]), logit[4]);
        m = fmaxf(fmaxf(m, logit[5]), logit[6]);
        m = fmaxf(m, logit[7]);

        float e[8];
        float sum = 0.0f;
        #pragma unroll
        for (int k = 0; k < 8; ++k) {
            e[k] = __builtin_amdgcn_exp2f(logit[k] - m);
            sum += e[k];
        }
        const float inv = K * __builtin_amdgcn_rcpf(sum);

        float q0 = 0.0f, q1 = 0.0f, q2 = 0.0f;
        #pragma unroll
        for (int k = 0; k < 8; ++k) {
            q0 = fmaf(e[k], w0[k], q0);
            q1 = fmaf(e[k], w1[k], q1);
            q2 = fmaf(e[k], w2[k], q2);
        }
        zo[g * 3 + 0] = q0 * inv;
        zo[g * 3 + 1] = q1 * inv;
        zo[g * 3 + 2] = q2 * inv;
    }

    buf[3 * t + 0] = make_float4(zo[0], zo[1],  zo[2],  zo[3]);
    buf[3 * t + 1] = make_float4(zo[4], zo[5],  zo[6],  zo[7]);
    buf[3 * t + 2] = make_float4(zo[8], zo[9],  zo[10], zo[11]);
    __syncthreads();

    // ---- coalesced LDS -> global, nontemporal (output never re-read) ----
    const floatx4* lsrc = reinterpret_cast<const floatx4*>(buf);
    floatx4* o = reinterpret_cast<floatx4*>(out) + base4;
    __builtin_nontemporal_store(lsrc[t],       &o[t]);
    __builtin_nontemporal_store(lsrc[t + 256], &o[t + 256]);
    __builtin_nontemporal_store(lsrc[t + 512], &o[t + 512]);
}

extern "C" void kernel_launch(void* const* d_in, const int* in_sizes, int n_in,
                              void* d_out, int out_size, void* d_ws, size_t ws_size,
                              hipStream_t stream) {
    const float* x     = (const float*)d_in[0];
    const float* delta = (const float*)d_in[1];
    const float* scale = (const float*)d_in[2];
    float* out = (float*)d_out;

    const int grid = out_size / 3072;  // 25,165,824 / 3072 = 8192 blocks exactly
    dq_kernel<<<grid, 256, 0, stream>>>(x, delta, scale, out);
}